// Round 5
// baseline (301.092 us; speedup 1.0000x reference)
//
#include <hip/hip_runtime.h>

// CTC loss forward (sum reduction). Shapes fixed: T=1000, B=64, V=512, S=100.
// Phase 1 (ctc_emit): em[b][t][s] = bf16( p(ext[s]) * 2^5 ), with validity
//   (s >= 2*tgt_len[b]+1 -> 0) BAKED IN (emit table is per-b). Row padded to
//   256 shorts = 512 B so one global_load_lds_dwordx4 stages two timesteps.
// Phase 2 (ctc_alpha): one wave per b. Async DMA global->LDS (3 buffers x
//   32 rows, s_waitcnt vmcnt(16) pipeline) -- prefetch lives in LDS, so the
//   compiler cannot collapse it (R2/R3/R4 all had register rings sunk).
//   Linear recursion: lane l owns states 4l..4l+3; one __shfl_up per step;
//   wave-max renorm every 16 steps (EMIT_SHIFT=5: growth <= (3*2^5)^16 =
//   2^105 < 2^127, deterministically safe). Exact compensation:
//   loss = -ln2 * (log2(sum) + rs - 5*Tin).

#define NEGF (-1e30f)

constexpr int CT_T  = 1000;
constexpr int CT_B  = 64;
constexpr int CT_V  = 512;
constexpr int CT_S  = 100;
constexpr int CT_Se = 201;
constexpr int CT_RB = 256;            // bf16 row stride = 512 B
constexpr int CT_TP = 1092;           // padded rows per b (DMA overrun, no clamp)
constexpr float LOG2E = 1.4426950408889634f;
constexpr float LN2   = 0.6931471805599453f;
constexpr float EMIT_SHIFT = 5.0f;

constexpr size_t EM_SHORTS = (size_t)CT_B * CT_TP * CT_RB;   // 17,891,328
constexpr size_t EM_BYTES  = EM_SHORTS * 2;                  // 35,782,656
constexpr size_t WS_NEEDED = EM_BYTES + 1024;

#if __has_builtin(__builtin_amdgcn_exp2f) && __has_builtin(__builtin_amdgcn_logf)
__device__ __forceinline__ float fexp2(float x) { return __builtin_amdgcn_exp2f(x); }
__device__ __forceinline__ float flog2(float x) { return __builtin_amdgcn_logf(x); }
__device__ __forceinline__ float frcp(float x)  { return __builtin_amdgcn_rcpf(x); }
#else
__device__ __forceinline__ float fexp2(float x) { return exp2f(x); }
__device__ __forceinline__ float flog2(float x) { return log2f(x); }
__device__ __forceinline__ float frcp(float x)  { return 1.0f / x; }
#endif

__device__ __forceinline__ float lae2_b2(float x, float y) {
    float m = fmaxf(x, y);
    float d = fminf(x, y) - m;
    return m + flog2(1.0f + fexp2(d));
}
__device__ __forceinline__ float lae3_b2(float x, float y, float z) {
    float m = fmaxf(fmaxf(x, y), z);
    float s = fexp2(x - m) + fexp2(y - m) + fexp2(z - m);
    return m + flog2(s);
}

typedef const __attribute__((address_space(1))) unsigned int* as1_uint_ptr;
typedef __attribute__((address_space(3))) unsigned int* as3_uint_ptr;
__device__ __forceinline__ void gld16(const void* g, void* l) {
    // stages 16 B/lane: LDS dest = (uniform) l + lane*16
    __builtin_amdgcn_global_load_lds((as1_uint_ptr)g, (as3_uint_ptr)l, 16, 0, 0);
}
__device__ __forceinline__ void waitcnt_vm16() { __builtin_amdgcn_s_waitcnt(0x4F70); }
__device__ __forceinline__ void waitcnt_vm0()  { __builtin_amdgcn_s_waitcnt(0x0F70); }

// ---------------- Phase 1: gather + scale + bf16, validity baked ----------------
__global__ __launch_bounds__(256) void ctc_emit(
    const float* __restrict__ logp,    // (T, B, V)
    const int*   __restrict__ tgt,     // (B, S)
    const int*   __restrict__ tgt_len, // (B,)
    unsigned short* __restrict__ em)   // (B, CT_TP, 256) bf16
{
    const int b    = blockIdx.y;
    const int t    = blockIdx.x * 4 + (threadIdx.x >> 6);
    const int lane = threadIdx.x & 63;
    if (lane >= 52) return;
    const int lim = 2 * tgt_len[b] + 1;      // states >= lim are dead for this b
    const int* tg = tgt + b * CT_S;
    const int s0 = 4 * lane;
    const int i1 = min(s0 >> 1, CT_S - 1);
    const int i3 = min((s0 + 2) >> 1, CT_S - 1);
    const int c1 = tg[i1], c3 = tg[i3];
    const float* src = logp + ((long long)t * CT_B + b) * CT_V;
    float pb = src[1];
    float p1 = src[c1];
    float p3 = src[c3];
    auto enc = [&](float lp, int s) -> unsigned short {
        if (s >= lim) return 0;
        float q = fexp2(fmaf(lp, LOG2E, EMIT_SHIFT));
        unsigned u = __float_as_uint(q);
        return (unsigned short)((u + 0x7fff + ((u >> 16) & 1)) >> 16);  // RNE
    };
    ushort4 o;
    o.x = enc(pb, s0);
    o.y = enc(p1, s0 + 1);
    o.z = enc(pb, s0 + 2);
    o.w = enc(p3, s0 + 3);
    *(ushort4*)(em + ((long long)b * CT_TP + t) * CT_RB + 4 * lane) = o;
}

// ---------------- Phase 2: linear recursion, LDS async-DMA pipeline ----------------
__global__ __launch_bounds__(64, 1) void ctc_alpha(
    const int* __restrict__ in_len,
    const int* __restrict__ tgt,
    const int* __restrict__ tgt_len,
    const unsigned short* __restrict__ em,   // (B, CT_TP, 256) bf16
    float* __restrict__ loss_ws)
{
    __shared__ unsigned short lds_em[3][32][CT_RB];   // 48 KiB

    const int b    = blockIdx.x;
    const int lane = threadIdx.x;
    const int Tin  = in_len[b];
    const int Lt   = tgt_len[b];
    const int* tg  = tgt + b * CT_S;

    const int s0 = 4 * lane, s1 = s0 + 1, s3 = s0 + 3;
    const int i1 = min((s1 - 1) >> 1, CT_S - 1);
    const int i3 = min((s3 - 1) >> 1, CT_S - 1);
    const int c1 = tg[i1];
    const int c3 = tg[i3];
    const float sk1 = ((s1 >= 3) && (s1 < CT_Se) && (c1 != tg[max(i1 - 1, 0)])) ? 1.f : 0.f;
    const float sk3 = ((s3 >= 3) && (s3 < CT_Se) && (c3 != tg[max(i3 - 1, 0)])) ? 1.f : 0.f;

    const unsigned short* emb = em + (size_t)b * CT_TP * CT_RB;
    const int ll = min(lane, 51);    // lanes 52..63 mirror lane 51 (dead states)

    // init from row 0 (validity baked into table)
    float a0 = 0.f, a1 = 0.f, a2 = 0.f, a3 = 0.f, pa3 = 0.f;
    if (lane == 0) {
        unsigned d0 = *(const unsigned*)emb;            // s=0 | s=1<<16
        a0 = __uint_as_float(d0 << 16);
        a1 = __uint_as_float(d0 & 0xffff0000u);
    }
    float rs = 0.f;   // accumulated renorm log2-scale (wave-uniform)

    // chunk k stages emit rows tb..tb+31, tb = 1+32k, via 16 dwordx4 DMAs
    auto issue = [&](int k, int buf) {
        const char* gb = (const char*)emb + (size_t)(1 + 32 * k) * (CT_RB * 2)
                       + (size_t)lane * 16;
        #pragma unroll
        for (int i = 0; i < 16; ++i)
            gld16(gb + (size_t)i * 1024, &lds_em[buf][2 * i][0]);
    };

    auto renorm = [&]() {
        float lm = fmaxf(fmaxf(a0, a1), fmaxf(a2, a3));
        #pragma unroll
        for (int off = 1; off < 64; off <<= 1)
            lm = fmaxf(lm, __shfl_xor(lm, off));
        if (lm > 0.f) {
            float sc = frcp(lm);
            rs += flog2(lm);
            a0 *= sc; a1 *= sc; a2 *= sc; a3 *= sc; pa3 *= sc;
        }
    };

    auto run16 = [&](int buf, int r0, int tb) {
        #pragma unroll
        for (int i = 0; i < 16; ++i) {
            uint2 d = *(const uint2*)(&lds_em[buf][r0 + i][4 * ll]);
            float ex = __uint_as_float(d.x << 16);
            float ey = __uint_as_float(d.x & 0xffff0000u);
            float ez = __uint_as_float(d.y << 16);
            float ew = __uint_as_float(d.y & 0xffff0000u);
            float n0 = (a0 + pa3) * ex;
            float n1 = fmaf(sk1, pa3, a1 + a0) * ey;
            float n2 = (a2 + a1) * ez;
            float n3 = fmaf(sk3, a1, a3 + a2) * ew;
            if (tb + i < Tin) { a0 = n0; a1 = n1; a2 = n2; a3 = n3; }  // uniform
            pa3 = __shfl_up(a3, 1);
            if (lane == 0) pa3 = 0.f;
        }
        renorm();
    };

    issue(0, 0);
    issue(1, 1);
    const int K = (Tin - 1 + 31) / 32;        // chunks of 32 steps (K in [16,32])
    for (int k = 0; k < K; ++k) {
        waitcnt_vm16();                        // chunk k landed (k+1 in flight)
        issue(k + 2, (k + 2) % 3);             // into the buffer freed by k-1
        const int tb = 1 + 32 * k;
        const int bf = k % 3;
        run16(bf, 0,  tb);
        run16(bf, 16, tb + 16);
    }
    waitcnt_vm0();   // drain DMA before LDS dealloc / endpgm

    const int last = 2 * Lt;
    const int prev = max(last - 1, 0);
    const int lr = last & 3, lidx = last >> 2;
    float av = (lr == 0) ? a0 : (lr == 1) ? a1 : (lr == 2) ? a2 : a3;
    float a_last = __shfl(av, lidx);
    const int pr = prev & 3, pidx = prev >> 2;
    float pv = (pr == 0) ? a0 : (pr == 1) ? a1 : (pr == 2) ? a2 : a3;
    float a_prev = __shfl(pv, pidx);

    float sum = a_last + a_prev;
    float loss = 0.f;
    if (sum > 0.f)
        loss = -(flog2(sum) + rs - EMIT_SHIFT * (float)Tin) * LN2;
    if (lane == 0) loss_ws[b] = loss;
}

// ---------------- Fallback (log-domain single pass, tiny ws) ----------------
__global__ __launch_bounds__(64) void ctc_alpha_fb(
    const float* __restrict__ logp, const int* __restrict__ in_len,
    const int* __restrict__ tgt, const int* __restrict__ tgt_len,
    float* __restrict__ loss_ws)
{
    const int b = blockIdx.x, lane = threadIdx.x;
    const int Tin = in_len[b], Lt = tgt_len[b];
    const int ext_len = 2 * Lt + 1;
    const int* tg = tgt + b * CT_S;
    const int s0 = 4 * lane, s1 = s0 + 1, s3 = s0 + 3;
    const int i1 = min((s1 - 1) >> 1, CT_S - 1);
    const int i3 = min((s3 - 1) >> 1, CT_S - 1);
    const int c1 = tg[i1], c3 = tg[i3];
    const bool skip1 = (s1 >= 3) && (s1 < CT_Se) && (c1 != tg[max(i1 - 1, 0)]);
    const bool skip3 = (s3 >= 3) && (s3 < CT_Se) && (c3 != tg[max(i3 - 1, 0)]);
    const bool v0 = s0 < ext_len, v1 = s1 < ext_len;
    const bool v2 = (s0 + 2) < ext_len, v3 = s3 < ext_len;
    const float* row0 = logp + (long long)b * CT_V;
    const long long stride = (long long)CT_B * CT_V;
    float a0 = NEGF, a1 = NEGF, a2 = NEGF, a3 = NEGF;
    if (lane == 0) {
        a0 = row0[1] * LOG2E;
        if (ext_len > 1) a1 = row0[c1] * LOG2E;
    }
    float3 E0, E1, E2, E3;
    auto ld = [&](float3& e, int t) {
        int tt = min(t, CT_T - 1);
        const float* r = row0 + (long long)tt * stride;
        e.x = r[1] * LOG2E; e.y = r[c1] * LOG2E; e.z = r[c3] * LOG2E;
    };
    auto step = [&](const float3& e) {
        float pa3 = __shfl_up(a3, 1);
        if (lane == 0) pa3 = NEGF;
        float z1 = skip1 ? pa3 : NEGF;
        float z3 = skip3 ? a1 : NEGF;
        float n0 = v0 ? lae2_b2(a0, pa3)    + e.x : NEGF;
        float n1 = v1 ? lae3_b2(a1, a0, z1) + e.y : NEGF;
        float n2 = v2 ? lae2_b2(a2, a1)     + e.x : NEGF;
        float n3 = v3 ? lae3_b2(a3, a2, z3) + e.z : NEGF;
        a0 = n0; a1 = n1; a2 = n2; a3 = n3;
    };
    ld(E0, 1); ld(E1, 2); ld(E2, 3); ld(E3, 4);
    for (int t = 1; t < Tin; t += 4) {
        step(E0); ld(E0, t + 4);
        if (t + 1 < Tin) { step(E1); ld(E1, t + 5); }
        if (t + 2 < Tin) { step(E2); ld(E2, t + 6); }
        if (t + 3 < Tin) { step(E3); ld(E3, t + 7); }
    }
    const int last = 2 * Lt, prev = max(last - 1, 0);
    const int lr = last & 3, lidx = last >> 2;
    float av = (lr == 0) ? a0 : (lr == 1) ? a1 : (lr == 2) ? a2 : a3;
    float a_last = __shfl(av, lidx);
    const int pr = prev & 3, pidx = prev >> 2;
    float pv = (pr == 0) ? a0 : (pr == 1) ? a1 : (pr == 2) ? a2 : a3;
    float a_prev = __shfl(pv, pidx);
    float loglik = lae2_b2(a_last, a_prev) * LN2;
    float loss = (loglik < 0.5f * NEGF) ? 0.0f : -loglik;
    if (lane == 0) loss_ws[b] = loss;
}

__global__ __launch_bounds__(64) void ctc_sum(const float* __restrict__ loss_ws,
                                              float* __restrict__ out)
{
    float v = loss_ws[threadIdx.x];
    #pragma unroll
    for (int o = 32; o > 0; o >>= 1) v += __shfl_down(v, o);
    if (threadIdx.x == 0) out[0] = v;
}

extern "C" void kernel_launch(void* const* d_in, const int* in_sizes, int n_in,
                              void* d_out, int out_size, void* d_ws, size_t ws_size,
                              hipStream_t stream) {
    const float* logp    = (const float*)d_in[0];
    const int*   in_len  = (const int*)d_in[1];
    const int*   tgt     = (const int*)d_in[2];
    const int*   tgt_len = (const int*)d_in[3];
    float* out = (float*)d_out;

    if (ws_size >= WS_NEEDED) {
        unsigned short* em = (unsigned short*)d_ws;
        float* loss_ws = (float*)((char*)d_ws + EM_BYTES);
        hipLaunchKernelGGL(ctc_emit, dim3(CT_T / 4, CT_B), dim3(256), 0, stream,
                           logp, tgt, tgt_len, em);
        hipLaunchKernelGGL(ctc_alpha, dim3(CT_B), dim3(64), 0, stream,
                           in_len, tgt, tgt_len, em, loss_ws);
        hipLaunchKernelGGL(ctc_sum, dim3(1), dim3(64), 0, stream, loss_ws, out);
    } else {
        float* loss_ws = (float*)d_ws;
        hipLaunchKernelGGL(ctc_alpha_fb, dim3(CT_B), dim3(64), 0, stream,
                           logp, in_len, tgt, tgt_len, loss_ws);
        hipLaunchKernelGGL(ctc_sum, dim3(1), dim3(64), 0, stream, loss_ws, out);
    }
}

// Round 6
// 247.948 us; speedup vs baseline: 1.2143x; 1.2143x over previous
//
#include <hip/hip_runtime.h>

// CTC loss forward (sum reduction). Shapes fixed: T=1000, B=64, V=512, S=100.
// Phase 1 (ctc_emit): coalesced full-row load -> LDS -> gather;
//   em[b][t][s] = bf16( p(ext[s]) * 2^5 ), validity (s >= 2*tgt_len+1 -> 0)
//   baked in. Rows t >= in_len[b] skipped (never committed by alpha).
// Phase 2 (ctc_alpha): one wave per b. Async DMA global->LDS (3 bufs x 32
//   rows, s_waitcnt vmcnt(16) pipeline). Linear recursion; lane l owns states
//   4l..4l+3. Cross-lane neighbor via DPP wave_shr1 (VALU, no DS op on the
//   serial chain -- R5's ds_bpermute was ~120 cyc/step). Wave-max renorm
//   every 16 steps via DPP row_shr/row_bcast reduce (alphas >= 0 so
//   bound_ctrl zero-fill is safe). loss = -ln2*(log2(sum) + rs - 5*Tin).

#define NEGF (-1e30f)

constexpr int CT_T  = 1000;
constexpr int CT_B  = 64;
constexpr int CT_V  = 512;
constexpr int CT_S  = 100;
constexpr int CT_Se = 201;
constexpr int CT_RB = 256;            // bf16 row stride = 512 B
constexpr int CT_TP = 1092;           // padded rows per b (DMA overrun, no clamp)
constexpr float LOG2E = 1.4426950408889634f;
constexpr float LN2   = 0.6931471805599453f;
constexpr float EMIT_SHIFT = 5.0f;

constexpr size_t EM_SHORTS = (size_t)CT_B * CT_TP * CT_RB;   // 17,891,328
constexpr size_t EM_BYTES  = EM_SHORTS * 2;                  // 35,782,656
constexpr size_t WS_NEEDED = EM_BYTES + 1024;

#if __has_builtin(__builtin_amdgcn_exp2f) && __has_builtin(__builtin_amdgcn_logf)
__device__ __forceinline__ float fexp2(float x) { return __builtin_amdgcn_exp2f(x); }
__device__ __forceinline__ float flog2(float x) { return __builtin_amdgcn_logf(x); }
__device__ __forceinline__ float frcp(float x)  { return __builtin_amdgcn_rcpf(x); }
#else
__device__ __forceinline__ float fexp2(float x) { return exp2f(x); }
__device__ __forceinline__ float flog2(float x) { return log2f(x); }
__device__ __forceinline__ float frcp(float x)  { return 1.0f / x; }
#endif

__device__ __forceinline__ float lae2_b2(float x, float y) {
    float m = fmaxf(x, y);
    float d = fminf(x, y) - m;
    return m + flog2(1.0f + fexp2(d));
}
__device__ __forceinline__ float lae3_b2(float x, float y, float z) {
    float m = fmaxf(fmaxf(x, y), z);
    float s = fexp2(x - m) + fexp2(y - m) + fexp2(z - m);
    return m + flog2(s);
}

// lane l <- lane l-1 (lane 0 <- 0). VALU-speed cross-lane (DPP wave_shr:1).
__device__ __forceinline__ float wave_shr1(float x) {
    return __int_as_float(__builtin_amdgcn_update_dpp(
        0, __float_as_int(x), 0x138, 0xf, 0xf, true));
}
// wave max of NON-NEGATIVE x, all-VALU (DPP). Result uniform via readlane 63.
__device__ __forceinline__ float wave_max_nonneg(float x) {
#define DPPMAX(ctrl) x = fmaxf(x, __int_as_float(__builtin_amdgcn_update_dpp( \
        0, __float_as_int(x), ctrl, 0xf, 0xf, true)))
    DPPMAX(0x111);  // row_shr:1
    DPPMAX(0x112);  // row_shr:2
    DPPMAX(0x114);  // row_shr:4
    DPPMAX(0x118);  // row_shr:8  -> lane 15/31/47/63 hold row maxes
    DPPMAX(0x142);  // row_bcast:15 -> lane 31 = max(r0,r1), lane 63 = max(r2,r3)
    DPPMAX(0x143);  // row_bcast:31 -> lane 63 = full max
#undef DPPMAX
    return __int_as_float(__builtin_amdgcn_readlane(__float_as_int(x), 63));
}

typedef const __attribute__((address_space(1))) unsigned int* as1_uint_ptr;
typedef __attribute__((address_space(3))) unsigned int* as3_uint_ptr;
__device__ __forceinline__ void gld16(const void* g, void* l) {
    __builtin_amdgcn_global_load_lds((as1_uint_ptr)g, (as3_uint_ptr)l, 16, 0, 0);
}
__device__ __forceinline__ void waitcnt_vm16() { __builtin_amdgcn_s_waitcnt(0x4F70); }
__device__ __forceinline__ void waitcnt_vm0()  { __builtin_amdgcn_s_waitcnt(0x0F70); }

// ---------------- Phase 1: coalesced row load + LDS gather ----------------
__global__ __launch_bounds__(256) void ctc_emit(
    const float* __restrict__ logp,    // (T, B, V)
    const int*   __restrict__ tgt,     // (B, S)
    const int*   __restrict__ tgt_len, // (B,)
    const int*   __restrict__ in_len,  // (B,)
    unsigned short* __restrict__ em)   // (B, CT_TP, 256) bf16
{
    __shared__ float rows[4][CT_V];
    const int b    = blockIdx.y;
    const int w    = threadIdx.x >> 6;          // wave id -> one t row
    const int lane = threadIdx.x & 63;
    const int t    = blockIdx.x * 4 + w;
    if (t >= in_len[b]) return;                 // rows >= Tin never committed

    const float* src = logp + ((long long)t * CT_B + b) * CT_V;
    float4 x0 = *(const float4*)(src + 8 * lane);
    float4 x1 = *(const float4*)(src + 8 * lane + 4);
    *(float4*)(&rows[w][8 * lane])     = x0;
    *(float4*)(&rows[w][8 * lane + 4]) = x1;
    // wave reads only its own LDS row: no __syncthreads needed.

    if (lane < 52) {
        const int lim = 2 * tgt_len[b] + 1;
        const int* tg = tgt + b * CT_S;
        const int s0 = 4 * lane;
        const int i1 = min(s0 >> 1, CT_S - 1);
        const int i3 = min((s0 + 2) >> 1, CT_S - 1);
        const int c1 = tg[i1], c3 = tg[i3];
        float pb = rows[w][1];
        float p1 = rows[w][c1];
        float p3 = rows[w][c3];
        auto enc = [&](float lp, int s) -> unsigned short {
            if (s >= lim) return 0;
            float q = fexp2(fmaf(lp, LOG2E, EMIT_SHIFT));
            unsigned u = __float_as_uint(q);
            return (unsigned short)((u + 0x7fff + ((u >> 16) & 1)) >> 16);  // RNE
        };
        ushort4 o;
        o.x = enc(pb, s0);
        o.y = enc(p1, s0 + 1);
        o.z = enc(pb, s0 + 2);
        o.w = enc(p3, s0 + 3);
        *(ushort4*)(em + ((long long)b * CT_TP + t) * CT_RB + 4 * lane) = o;
    }
}

// ---------------- Phase 2: linear recursion, DPP cross-lane ----------------
__global__ __launch_bounds__(64, 1) void ctc_alpha(
    const int* __restrict__ in_len,
    const int* __restrict__ tgt,
    const int* __restrict__ tgt_len,
    const unsigned short* __restrict__ em,   // (B, CT_TP, 256) bf16
    float* __restrict__ loss_ws)
{
    __shared__ unsigned short lds_em[3][32][CT_RB];   // 48 KiB

    const int b    = blockIdx.x;
    const int lane = threadIdx.x;
    const int Tin  = in_len[b];
    const int Lt   = tgt_len[b];
    const int* tg  = tgt + b * CT_S;

    const int s0 = 4 * lane, s1 = s0 + 1, s3 = s0 + 3;
    const int i1 = min((s1 - 1) >> 1, CT_S - 1);
    const int i3 = min((s3 - 1) >> 1, CT_S - 1);
    const int c1 = tg[i1];
    const int c3 = tg[i3];
    const float sk1 = ((s1 >= 3) && (s1 < CT_Se) && (c1 != tg[max(i1 - 1, 0)])) ? 1.f : 0.f;
    const float sk3 = ((s3 >= 3) && (s3 < CT_Se) && (c3 != tg[max(i3 - 1, 0)])) ? 1.f : 0.f;

    const unsigned short* emb = em + (size_t)b * CT_TP * CT_RB;
    const int ll = min(lane, 51);    // lanes 52..63 mirror lane 51 (dead states)

    float a0 = 0.f, a1 = 0.f, a2 = 0.f, a3 = 0.f, pa3 = 0.f;
    if (lane == 0) {
        unsigned d0 = *(const unsigned*)emb;            // row 0: s=0 | s=1<<16
        a0 = __uint_as_float(d0 << 16);
        a1 = __uint_as_float(d0 & 0xffff0000u);
    }
    float rs = 0.f;   // accumulated renorm log2-scale (wave-uniform)

    auto issue = [&](int k, int buf) {
        const char* gb = (const char*)emb + (size_t)(1 + 32 * k) * (CT_RB * 2)
                       + (size_t)lane * 16;
        #pragma unroll
        for (int i = 0; i < 16; ++i)
            gld16(gb + (size_t)i * 1024, &lds_em[buf][2 * i][0]);
    };

    auto renorm = [&]() {
        float lm = wave_max_nonneg(fmaxf(fmaxf(a0, a1), fmaxf(a2, a3)));
        if (lm > 0.f) {
            float sc = frcp(lm);
            rs += flog2(lm);
            a0 *= sc; a1 *= sc; a2 *= sc; a3 *= sc;
            pa3 = wave_shr1(a3);
        }
    };

    #define UNPACK(d, ex, ey, ez, ew) \
        float ex = __uint_as_float((d).x << 16); \
        float ey = __uint_as_float((d).x & 0xffff0000u); \
        float ez = __uint_as_float((d).y << 16); \
        float ew = __uint_as_float((d).y & 0xffff0000u)

    auto run16 = [&](int buf, int r0, int tb, bool guard) {
        uint2 d[16];
        #pragma unroll
        for (int i = 0; i < 16; ++i)
            d[i] = *(const uint2*)(&lds_em[buf][r0 + i][4 * ll]);
        if (!guard) {
            #pragma unroll
            for (int i = 0; i < 16; ++i) {
                UNPACK(d[i], ex, ey, ez, ew);
                float n0 = (a0 + pa3) * ex;
                float n1 = fmaf(sk1, pa3, a1 + a0) * ey;
                float n2 = (a2 + a1) * ez;
                float n3 = fmaf(sk3, a1, a3 + a2) * ew;
                a0 = n0; a1 = n1; a2 = n2; a3 = n3;
                pa3 = wave_shr1(a3);
            }
        } else {
            #pragma unroll
            for (int i = 0; i < 16; ++i) {
                UNPACK(d[i], ex, ey, ez, ew);
                float n0 = (a0 + pa3) * ex;
                float n1 = fmaf(sk1, pa3, a1 + a0) * ey;
                float n2 = (a2 + a1) * ez;
                float n3 = fmaf(sk3, a1, a3 + a2) * ew;
                if (tb + i < Tin) { a0 = n0; a1 = n1; a2 = n2; a3 = n3; }
                pa3 = wave_shr1(a3);
            }
        }
        renorm();
    };

    issue(0, 0);
    issue(1, 1);
    const int Kf = (Tin - 1) / 32;            // full (unguarded) chunks
    const int K  = (Tin - 1 + 31) / 32;       // total chunks
    for (int k = 0; k < Kf; ++k) {
        waitcnt_vm16();                        // chunk k landed (k+1 in flight)
        issue(k + 2, (k + 2) % 3);
        const int bf = k % 3;
        run16(bf, 0,  0, false);
        run16(bf, 16, 0, false);
    }
    if (K > Kf) {                              // guarded tail chunk
        waitcnt_vm16();
        const int tb = 1 + 32 * Kf;
        const int bf = Kf % 3;
        run16(bf, 0,  tb,      true);
        run16(bf, 16, tb + 16, true);
    }
    waitcnt_vm0();   // drain DMA before endpgm

    const int last = 2 * Lt;
    const int prev = max(last - 1, 0);
    const int lr = last & 3, lidx = last >> 2;
    float av = (lr == 0) ? a0 : (lr == 1) ? a1 : (lr == 2) ? a2 : a3;
    float a_last = __shfl(av, lidx);
    const int pr = prev & 3, pidx = prev >> 2;
    float pv = (pr == 0) ? a0 : (pr == 1) ? a1 : (pr == 2) ? a2 : a3;
    float a_prev = __shfl(pv, pidx);

    float sum = a_last + a_prev;
    float loss = 0.f;
    if (sum > 0.f)
        loss = -(flog2(sum) + rs - EMIT_SHIFT * (float)Tin) * LN2;
    if (lane == 0) loss_ws[b] = loss;
}

// ---------------- Fallback (log-domain single pass, tiny ws) ----------------
__global__ __launch_bounds__(64) void ctc_alpha_fb(
    const float* __restrict__ logp, const int* __restrict__ in_len,
    const int* __restrict__ tgt, const int* __restrict__ tgt_len,
    float* __restrict__ loss_ws)
{
    const int b = blockIdx.x, lane = threadIdx.x;
    const int Tin = in_len[b], Lt = tgt_len[b];
    const int ext_len = 2 * Lt + 1;
    const int* tg = tgt + b * CT_S;
    const int s0 = 4 * lane, s1 = s0 + 1, s3 = s0 + 3;
    const int i1 = min((s1 - 1) >> 1, CT_S - 1);
    const int i3 = min((s3 - 1) >> 1, CT_S - 1);
    const int c1 = tg[i1], c3 = tg[i3];
    const bool skip1 = (s1 >= 3) && (s1 < CT_Se) && (c1 != tg[max(i1 - 1, 0)]);
    const bool skip3 = (s3 >= 3) && (s3 < CT_Se) && (c3 != tg[max(i3 - 1, 0)]);
    const bool v0 = s0 < ext_len, v1 = s1 < ext_len;
    const bool v2 = (s0 + 2) < ext_len, v3 = s3 < ext_len;
    const float* row0 = logp + (long long)b * CT_V;
    const long long stride = (long long)CT_B * CT_V;
    float a0 = NEGF, a1 = NEGF, a2 = NEGF, a3 = NEGF;
    if (lane == 0) {
        a0 = row0[1] * LOG2E;
        if (ext_len > 1) a1 = row0[c1] * LOG2E;
    }
    float3 E0, E1, E2, E3;
    auto ld = [&](float3& e, int t) {
        int tt = min(t, CT_T - 1);
        const float* r = row0 + (long long)tt * stride;
        e.x = r[1] * LOG2E; e.y = r[c1] * LOG2E; e.z = r[c3] * LOG2E;
    };
    auto step = [&](const float3& e) {
        float pa3 = __shfl_up(a3, 1);
        if (lane == 0) pa3 = NEGF;
        float z1 = skip1 ? pa3 : NEGF;
        float z3 = skip3 ? a1 : NEGF;
        float n0 = v0 ? lae2_b2(a0, pa3)    + e.x : NEGF;
        float n1 = v1 ? lae3_b2(a1, a0, z1) + e.y : NEGF;
        float n2 = v2 ? lae2_b2(a2, a1)     + e.x : NEGF;
        float n3 = v3 ? lae3_b2(a3, a2, z3) + e.z : NEGF;
        a0 = n0; a1 = n1; a2 = n2; a3 = n3;
    };
    ld(E0, 1); ld(E1, 2); ld(E2, 3); ld(E3, 4);
    for (int t = 1; t < Tin; t += 4) {
        step(E0); ld(E0, t + 4);
        if (t + 1 < Tin) { step(E1); ld(E1, t + 5); }
        if (t + 2 < Tin) { step(E2); ld(E2, t + 6); }
        if (t + 3 < Tin) { step(E3); ld(E3, t + 7); }
    }
    const int last = 2 * Lt, prev = max(last - 1, 0);
    const int lr = last & 3, lidx = last >> 2;
    float av = (lr == 0) ? a0 : (lr == 1) ? a1 : (lr == 2) ? a2 : a3;
    float a_last = __shfl(av, lidx);
    const int pr = prev & 3, pidx = prev >> 2;
    float pv = (pr == 0) ? a0 : (pr == 1) ? a1 : (pr == 2) ? a2 : a3;
    float a_prev = __shfl(pv, pidx);
    float loglik = lae2_b2(a_last, a_prev) * LN2;
    float loss = (loglik < 0.5f * NEGF) ? 0.0f : -loglik;
    if (lane == 0) loss_ws[b] = loss;
}

__global__ __launch_bounds__(64) void ctc_sum(const float* __restrict__ loss_ws,
                                              float* __restrict__ out)
{
    float v = loss_ws[threadIdx.x];
    #pragma unroll
    for (int o = 32; o > 0; o >>= 1) v += __shfl_down(v, o);
    if (threadIdx.x == 0) out[0] = v;
}

extern "C" void kernel_launch(void* const* d_in, const int* in_sizes, int n_in,
                              void* d_out, int out_size, void* d_ws, size_t ws_size,
                              hipStream_t stream) {
    const float* logp    = (const float*)d_in[0];
    const int*   in_len  = (const int*)d_in[1];
    const int*   tgt     = (const int*)d_in[2];
    const int*   tgt_len = (const int*)d_in[3];
    float* out = (float*)d_out;

    if (ws_size >= WS_NEEDED) {
        unsigned short* em = (unsigned short*)d_ws;
        float* loss_ws = (float*)((char*)d_ws + EM_BYTES);
        hipLaunchKernelGGL(ctc_emit, dim3(CT_T / 4, CT_B), dim3(256), 0, stream,
                           logp, tgt, tgt_len, in_len, em);
        hipLaunchKernelGGL(ctc_alpha, dim3(CT_B), dim3(64), 0, stream,
                           in_len, tgt, tgt_len, em, loss_ws);
        hipLaunchKernelGGL(ctc_sum, dim3(1), dim3(64), 0, stream, loss_ws, out);
    } else {
        float* loss_ws = (float*)d_ws;
        hipLaunchKernelGGL(ctc_alpha_fb, dim3(CT_B), dim3(64), 0, stream,
                           logp, in_len, tgt, tgt_len, loss_ws);
        hipLaunchKernelGGL(ctc_sum, dim3(1), dim3(64), 0, stream, loss_ws, out);
    }
}

// Round 7
// 235.947 us; speedup vs baseline: 1.2761x; 1.0509x over previous
//
#include <hip/hip_runtime.h>

// CTC loss forward (sum reduction). Shapes fixed: T=1000, B=64, V=512, S=100.
// SINGLE-PASS fused kernel: one wave per batch element b.
//   - Async DMA (global_load_lds, 16B) streams raw logp rows (T,B,V) -> LDS:
//     4 buffers x 8 rows x 2048 B (64 KiB), 16 DMAs/chunk, <=48 outstanding,
//     s_waitcnt vmcnt(32) pipeline. Compiler cannot collapse DMA prefetch
//     (register rings got sunk in R2-R4; DS latency killed R5 -> DPP in R6).
//   - Per chunk: gather 2 scattered + 1 broadcast LDS reads per step, exp2
//     (off the serial chain), then 8 recursion steps. Cross-lane neighbor via
//     DPP wave_shr:1 (VALU speed). Lane l owns states 4l..4l+3.
//   - Linear domain with 2^5 per-step scale, wave-max DPP renorm every 2
//     chunks; exact compensation: loss = -ln2*(log2(sum) + rs - 5*Tin).

#define NEGF (-1e30f)

constexpr int CT_T  = 1000;
constexpr int CT_B  = 64;
constexpr int CT_V  = 512;
constexpr int CT_S  = 100;
constexpr int CT_Se = 201;
constexpr float LOG2E = 1.4426950408889634f;
constexpr float LN2   = 0.6931471805599453f;
constexpr float SHIFT = 5.0f;

#if __has_builtin(__builtin_amdgcn_exp2f) && __has_builtin(__builtin_amdgcn_logf)
__device__ __forceinline__ float fexp2(float x) { return __builtin_amdgcn_exp2f(x); }
__device__ __forceinline__ float flog2(float x) { return __builtin_amdgcn_logf(x); }
__device__ __forceinline__ float frcp(float x)  { return __builtin_amdgcn_rcpf(x); }
#else
__device__ __forceinline__ float fexp2(float x) { return exp2f(x); }
__device__ __forceinline__ float flog2(float x) { return log2f(x); }
__device__ __forceinline__ float frcp(float x)  { return 1.0f / x; }
#endif

__device__ __forceinline__ float lae2_b2(float x, float y) {
    float m = fmaxf(x, y);
    float d = fminf(x, y) - m;
    return m + flog2(1.0f + fexp2(d));
}
__device__ __forceinline__ float lae3_b2(float x, float y, float z) {
    float m = fmaxf(fmaxf(x, y), z);
    float s = fexp2(x - m) + fexp2(y - m) + fexp2(z - m);
    return m + flog2(s);
}

// lane l <- lane l-1 (lane 0 <- 0): DPP wave_shr:1, VALU speed.
__device__ __forceinline__ float wave_shr1(float x) {
    return __int_as_float(__builtin_amdgcn_update_dpp(
        0, __float_as_int(x), 0x138, 0xf, 0xf, true));
}
// wave max of NON-NEGATIVE x, all-VALU DPP reduce; uniform via readlane 63.
__device__ __forceinline__ float wave_max_nonneg(float x) {
#define DPPMAX(ctrl) x = fmaxf(x, __int_as_float(__builtin_amdgcn_update_dpp( \
        0, __float_as_int(x), ctrl, 0xf, 0xf, true)))
    DPPMAX(0x111); DPPMAX(0x112); DPPMAX(0x114); DPPMAX(0x118);
    DPPMAX(0x142); DPPMAX(0x143);
#undef DPPMAX
    return __int_as_float(__builtin_amdgcn_readlane(__float_as_int(x), 63));
}

typedef const __attribute__((address_space(1))) unsigned int* as1_uint_ptr;
typedef __attribute__((address_space(3))) unsigned int* as3_uint_ptr;
__device__ __forceinline__ void gld16(const void* g, void* l) {
    __builtin_amdgcn_global_load_lds((as1_uint_ptr)g, (as3_uint_ptr)l, 16, 0, 0);
}
__device__ __forceinline__ void waitcnt_vm32() { __builtin_amdgcn_s_waitcnt(0x8F70); }
__device__ __forceinline__ void waitcnt_vm0()  { __builtin_amdgcn_s_waitcnt(0x0F70); }

// ---------------- fused recursion ----------------
__global__ __launch_bounds__(64, 1) void ctc_alpha(
    const float* __restrict__ logp,    // (T, B, V)
    const int*   __restrict__ in_len,
    const int*   __restrict__ tgt,
    const int*   __restrict__ tgt_len,
    float*       __restrict__ loss_ws)
{
    __shared__ float ldsr[4][8][CT_V];   // 64 KiB: 4 bufs x 8 rows x 2048 B

    const int b    = blockIdx.x;
    const int lane = threadIdx.x;
    const int Tin  = in_len[b];
    const int Lt   = tgt_len[b];
    const int lim  = 2 * Lt + 1;
    const int* tg  = tgt + b * CT_S;

    const int s0 = 4 * lane, s1 = s0 + 1, s3 = s0 + 3;
    const int i1 = min((s1 - 1) >> 1, CT_S - 1);
    const int i3 = min((s3 - 1) >> 1, CT_S - 1);
    const int c1 = tg[i1];
    const int c3 = tg[i3];
    const float sk1 = ((s1 >= 3) && (s1 < CT_Se) && (c1 != tg[max(i1 - 1, 0)])) ? 1.f : 0.f;
    const float sk3 = ((s3 >= 3) && (s3 < CT_Se) && (c3 != tg[max(i3 - 1, 0)])) ? 1.f : 0.f;
    const float m0 = (s0     < lim) ? 1.f : 0.f;
    const float m1 = (s0 + 1 < lim) ? 1.f : 0.f;
    const float m2 = (s0 + 2 < lim) ? 1.f : 0.f;
    const float m3 = (s0 + 3 < lim) ? 1.f : 0.f;

    // init alpha from t=0 (scaled by 2^SHIFT)
    float a0 = 0.f, a1 = 0.f, a2 = 0.f, a3 = 0.f, pa3 = 0.f;
    if (lane == 0) {
        const float* r0 = logp + (size_t)b * CT_V;
        a0 = fexp2(fmaf(r0[1], LOG2E, SHIFT));
        if (Lt > 0) a1 = fexp2(fmaf(r0[c1], LOG2E, SHIFT));
    }
    float rs = 0.f;   // accumulated renorm log2-scale (wave-uniform)

    // chunk k = timesteps 1+8k .. 8+8k; 16 DMAs (2 per 2048 B row)
    auto issue = [&](int k, int buf) {
        const int tb = 1 + 8 * k;
        #pragma unroll
        for (int i = 0; i < 8; ++i) {
            const int t = min(tb + i, CT_T - 1);
            const char* g = (const char*)(logp + ((size_t)t * CT_B + b) * CT_V)
                          + (size_t)lane * 16;
            gld16(g,        &ldsr[buf][i][0]);
            gld16(g + 1024, &ldsr[buf][i][256]);
        }
    };

    auto renorm = [&]() {
        float lm = wave_max_nonneg(fmaxf(fmaxf(a0, a1), fmaxf(a2, a3)));
        if (lm > 0.f) {
            float sc = frcp(lm);
            rs += flog2(lm);
            a0 *= sc; a1 *= sc; a2 *= sc; a3 *= sc;
            pa3 = wave_shr1(a3);
        }
    };

    auto run8 = [&](int buf, int tb, bool guard) {
        // gather + exp2 off the serial chain
        float eb[8], e1[8], e3[8];
        #pragma unroll
        for (int i = 0; i < 8; ++i) {
            float lb = ldsr[buf][i][1];     // broadcast (same addr all lanes)
            float l1 = ldsr[buf][i][c1];
            float l3 = ldsr[buf][i][c3];
            eb[i] = fexp2(fmaf(lb, LOG2E, SHIFT));
            e1[i] = fexp2(fmaf(l1, LOG2E, SHIFT));
            e3[i] = fexp2(fmaf(l3, LOG2E, SHIFT));
        }
        #pragma unroll
        for (int i = 0; i < 8; ++i) {
            float ex = eb[i] * m0, ey = e1[i] * m1;
            float ez = eb[i] * m2, ew = e3[i] * m3;
            float n0 = (a0 + pa3) * ex;
            float n1 = fmaf(sk1, pa3, a1 + a0) * ey;
            float n2 = (a2 + a1) * ez;
            float n3 = fmaf(sk3, a1, a3 + a2) * ew;
            if (!guard || (tb + i < Tin)) { a0 = n0; a1 = n1; a2 = n2; a3 = n3; }
            pa3 = wave_shr1(a3);
        }
    };

    issue(0, 0); issue(1, 1); issue(2, 2);          // 48 DMAs in flight
    const int Kf = (Tin - 1) / 8;                   // full chunks
    const int K  = (Tin - 1 + 7) / 8;               // total chunks
    for (int k = 0; k < Kf; ++k) {
        waitcnt_vm32();                             // chunk k landed
        issue(k + 3, (k + 3) & 3);                  // into buffer freed by k-1
        run8(k & 3, 0, false);
        if (k & 1) renorm();
    }
    if (K > Kf) {                                   // guarded tail chunk
        waitcnt_vm32();
        run8(Kf & 3, 1 + 8 * Kf, true);
    }
    waitcnt_vm0();                                  // drain DMA before endpgm

    const int last = 2 * Lt;
    const int prev = max(last - 1, 0);
    const int lr = last & 3, lidx = last >> 2;
    float av = (lr == 0) ? a0 : (lr == 1) ? a1 : (lr == 2) ? a2 : a3;
    float a_last = __shfl(av, lidx);
    const int pr = prev & 3, pidx = prev >> 2;
    float pv = (pr == 0) ? a0 : (pr == 1) ? a1 : (pr == 2) ? a2 : a3;
    float a_prev = __shfl(pv, pidx);

    float sum = a_last + a_prev;
    float loss = 0.f;
    if (sum > 0.f)
        loss = -(flog2(sum) + rs - SHIFT * (float)Tin) * LN2;
    if (lane == 0) loss_ws[b] = loss;
}

// ---------------- Fallback (log-domain single pass) ----------------
__global__ __launch_bounds__(64) void ctc_alpha_fb(
    const float* __restrict__ logp, const int* __restrict__ in_len,
    const int* __restrict__ tgt, const int* __restrict__ tgt_len,
    float* __restrict__ loss_ws)
{
    const int b = blockIdx.x, lane = threadIdx.x;
    const int Tin = in_len[b], Lt = tgt_len[b];
    const int ext_len = 2 * Lt + 1;
    const int* tg = tgt + b * CT_S;
    const int s0 = 4 * lane, s1 = s0 + 1, s3 = s0 + 3;
    const int i1 = min((s1 - 1) >> 1, CT_S - 1);
    const int i3 = min((s3 - 1) >> 1, CT_S - 1);
    const int c1 = tg[i1], c3 = tg[i3];
    const bool skip1 = (s1 >= 3) && (s1 < CT_Se) && (c1 != tg[max(i1 - 1, 0)]);
    const bool skip3 = (s3 >= 3) && (s3 < CT_Se) && (c3 != tg[max(i3 - 1, 0)]);
    const bool v0 = s0 < ext_len, v1 = s1 < ext_len;
    const bool v2 = (s0 + 2) < ext_len, v3 = s3 < ext_len;
    const float* row0 = logp + (long long)b * CT_V;
    const long long stride = (long long)CT_B * CT_V;
    float a0 = NEGF, a1 = NEGF, a2 = NEGF, a3 = NEGF;
    if (lane == 0) {
        a0 = row0[1] * LOG2E;
        if (ext_len > 1) a1 = row0[c1] * LOG2E;
    }
    float3 E0, E1, E2, E3;
    auto ld = [&](float3& e, int t) {
        int tt = min(t, CT_T - 1);
        const float* r = row0 + (long long)tt * stride;
        e.x = r[1] * LOG2E; e.y = r[c1] * LOG2E; e.z = r[c3] * LOG2E;
    };
    auto step = [&](const float3& e) {
        float pa3 = __shfl_up(a3, 1);
        if (lane == 0) pa3 = NEGF;
        float z1 = skip1 ? pa3 : NEGF;
        float z3 = skip3 ? a1 : NEGF;
        float n0 = v0 ? lae2_b2(a0, pa3)    + e.x : NEGF;
        float n1 = v1 ? lae3_b2(a1, a0, z1) + e.y : NEGF;
        float n2 = v2 ? lae2_b2(a2, a1)     + e.x : NEGF;
        float n3 = v3 ? lae3_b2(a3, a2, z3) + e.z : NEGF;
        a0 = n0; a1 = n1; a2 = n2; a3 = n3;
    };
    ld(E0, 1); ld(E1, 2); ld(E2, 3); ld(E3, 4);
    for (int t = 1; t < Tin; t += 4) {
        step(E0); ld(E0, t + 4);
        if (t + 1 < Tin) { step(E1); ld(E1, t + 5); }
        if (t + 2 < Tin) { step(E2); ld(E2, t + 6); }
        if (t + 3 < Tin) { step(E3); ld(E3, t + 7); }
    }
    const int last = 2 * Lt, prev = max(last - 1, 0);
    const int lr = last & 3, lidx = last >> 2;
    float av = (lr == 0) ? a0 : (lr == 1) ? a1 : (lr == 2) ? a2 : a3;
    float a_last = __shfl(av, lidx);
    const int pr = prev & 3, pidx = prev >> 2;
    float pv = (pr == 0) ? a0 : (pr == 1) ? a1 : (pr == 2) ? a2 : a3;
    float a_prev = __shfl(pv, pidx);
    float loglik = lae2_b2(a_last, a_prev) * LN2;
    float loss = (loglik < 0.5f * NEGF) ? 0.0f : -loglik;
    if (lane == 0) loss_ws[b] = loss;
}

__global__ __launch_bounds__(64) void ctc_sum(const float* __restrict__ loss_ws,
                                              float* __restrict__ out)
{
    float v = loss_ws[threadIdx.x];
    #pragma unroll
    for (int o = 32; o > 0; o >>= 1) v += __shfl_down(v, o);
    if (threadIdx.x == 0) out[0] = v;
}

extern "C" void kernel_launch(void* const* d_in, const int* in_sizes, int n_in,
                              void* d_out, int out_size, void* d_ws, size_t ws_size,
                              hipStream_t stream) {
    const float* logp    = (const float*)d_in[0];
    const int*   in_len  = (const int*)d_in[1];
    const int*   tgt     = (const int*)d_in[2];
    const int*   tgt_len = (const int*)d_in[3];
    float* out = (float*)d_out;
    float* loss_ws = (float*)d_ws;   // needs only 256 B

    if (ws_size >= 256 * sizeof(float)) {
        hipLaunchKernelGGL(ctc_alpha, dim3(CT_B), dim3(64), 0, stream,
                           logp, in_len, tgt, tgt_len, loss_ws);
    } else {
        hipLaunchKernelGGL(ctc_alpha_fb, dim3(CT_B), dim3(64), 0, stream,
                           logp, in_len, tgt, tgt_len, loss_ws);
    }
    hipLaunchKernelGGL(ctc_sum, dim3(1), dim3(64), 0, stream, loss_ws, out);
}

// Round 8
// 228.269 us; speedup vs baseline: 1.3190x; 1.0336x over previous
//
#include <hip/hip_runtime.h>

// CTC loss forward (sum reduction). Shapes fixed: T=1000, B=64, V=512, S=100.
// SINGLE-PASS fused kernel: one wave per batch element b.
//   - Async DMA (global_load_lds, 16B) streams raw logp rows -> LDS: 4 bufs x
//     8 rows x 2048 B, 48 DMAs outstanding, s_waitcnt vmcnt(32) pipeline.
//   - Per chunk: ONE inline-asm block issues all 24 ds_read_b32 (blank/c1/c3
//     x 8 rows) + s_waitcnt lgkmcnt(0). R4-R7 evidence: the scheduler sinks
//     per-step LDS reads next to uses -> one ~120-cyc DS round-trip per step;
//     the asm block forces batch issue so latency amortizes over 8 steps.
//   - exp2 gather->emit off the serial chain; recursion via DPP wave_shr:1.
//   - Linear domain, 2^5/step scale, DPP wave-max renorm every 2 chunks;
//     loss = -ln2*(log2(sum) + rs - 5*Tin).

#define NEGF (-1e30f)

constexpr int CT_T  = 1000;
constexpr int CT_B  = 64;
constexpr int CT_V  = 512;
constexpr int CT_S  = 100;
constexpr int CT_Se = 201;
constexpr float LOG2E = 1.4426950408889634f;
constexpr float LN2   = 0.6931471805599453f;
constexpr float SHIFT = 5.0f;

#if __has_builtin(__builtin_amdgcn_exp2f) && __has_builtin(__builtin_amdgcn_logf)
__device__ __forceinline__ float fexp2(float x) { return __builtin_amdgcn_exp2f(x); }
__device__ __forceinline__ float flog2(float x) { return __builtin_amdgcn_logf(x); }
__device__ __forceinline__ float frcp(float x)  { return __builtin_amdgcn_rcpf(x); }
#else
__device__ __forceinline__ float fexp2(float x) { return exp2f(x); }
__device__ __forceinline__ float flog2(float x) { return log2f(x); }
__device__ __forceinline__ float frcp(float x)  { return 1.0f / x; }
#endif

__device__ __forceinline__ float lae2_b2(float x, float y) {
    float m = fmaxf(x, y);
    float d = fminf(x, y) - m;
    return m + flog2(1.0f + fexp2(d));
}
__device__ __forceinline__ float lae3_b2(float x, float y, float z) {
    float m = fmaxf(fmaxf(x, y), z);
    float s = fexp2(x - m) + fexp2(y - m) + fexp2(z - m);
    return m + flog2(s);
}

// lane l <- lane l-1 (lane 0 <- 0): DPP wave_shr:1, VALU speed.
__device__ __forceinline__ float wave_shr1(float x) {
    return __int_as_float(__builtin_amdgcn_update_dpp(
        0, __float_as_int(x), 0x138, 0xf, 0xf, true));
}
// wave max of NON-NEGATIVE x, all-VALU DPP reduce; uniform via readlane 63.
__device__ __forceinline__ float wave_max_nonneg(float x) {
#define DPPMAX(ctrl) x = fmaxf(x, __int_as_float(__builtin_amdgcn_update_dpp( \
        0, __float_as_int(x), ctrl, 0xf, 0xf, true)))
    DPPMAX(0x111); DPPMAX(0x112); DPPMAX(0x114); DPPMAX(0x118);
    DPPMAX(0x142); DPPMAX(0x143);
#undef DPPMAX
    return __int_as_float(__builtin_amdgcn_readlane(__float_as_int(x), 63));
}

typedef const __attribute__((address_space(1))) unsigned int* as1_uint_ptr;
typedef __attribute__((address_space(3))) unsigned int* as3_uint_ptr;
__device__ __forceinline__ void gld16(const void* g, void* l) {
    __builtin_amdgcn_global_load_lds((as1_uint_ptr)g, (as3_uint_ptr)l, 16, 0, 0);
}
__device__ __forceinline__ void waitcnt_vm32() { __builtin_amdgcn_s_waitcnt(0x8F70); }
__device__ __forceinline__ void waitcnt_vm0()  { __builtin_amdgcn_s_waitcnt(0x0F70); }

// ---------------- fused recursion ----------------
__global__ __launch_bounds__(64, 1) void ctc_alpha(
    const float* __restrict__ logp,    // (T, B, V)
    const int*   __restrict__ in_len,
    const int*   __restrict__ tgt,
    const int*   __restrict__ tgt_len,
    float*       __restrict__ loss_ws)
{
    __shared__ float ldsr[4][8][CT_V];   // 64 KiB: 4 bufs x 8 rows x 2048 B

    const int b    = blockIdx.x;
    const int lane = threadIdx.x;
    const int Tin  = in_len[b];
    const int Lt   = tgt_len[b];
    const int lim  = 2 * Lt + 1;
    const int* tg  = tgt + b * CT_S;

    const int s0 = 4 * lane, s1 = s0 + 1, s3 = s0 + 3;
    const int i1 = min((s1 - 1) >> 1, CT_S - 1);
    const int i3 = min((s3 - 1) >> 1, CT_S - 1);
    const int c1 = tg[i1];
    const int c3 = tg[i3];
    const float sk1 = ((s1 >= 3) && (s1 < CT_Se) && (c1 != tg[max(i1 - 1, 0)])) ? 1.f : 0.f;
    const float sk3 = ((s3 >= 3) && (s3 < CT_Se) && (c3 != tg[max(i3 - 1, 0)])) ? 1.f : 0.f;
    const float m0 = (s0     < lim) ? 1.f : 0.f;
    const float m1 = (s0 + 1 < lim) ? 1.f : 0.f;
    const float m2 = (s0 + 2 < lim) ? 1.f : 0.f;
    const float m3 = (s0 + 3 < lim) ? 1.f : 0.f;

    float a0 = 0.f, a1 = 0.f, a2 = 0.f, a3 = 0.f, pa3 = 0.f;
    if (lane == 0) {
        const float* r0 = logp + (size_t)b * CT_V;
        a0 = fexp2(fmaf(r0[1], LOG2E, SHIFT));
        if (Lt > 0) a1 = fexp2(fmaf(r0[c1], LOG2E, SHIFT));
    }
    float rs = 0.f;   // accumulated renorm log2-scale (wave-uniform)

    auto issue = [&](int k, int buf) {
        const int tb = 1 + 8 * k;
        #pragma unroll
        for (int i = 0; i < 8; ++i) {
            const int t = min(tb + i, CT_T - 1);
            const char* g = (const char*)(logp + ((size_t)t * CT_B + b) * CT_V)
                          + (size_t)lane * 16;
            gld16(g,        &ldsr[buf][i][0]);
            gld16(g + 1024, &ldsr[buf][i][256]);
        }
    };

    auto renorm = [&]() {
        float lm = wave_max_nonneg(fmaxf(fmaxf(a0, a1), fmaxf(a2, a3)));
        if (lm > 0.f) {
            float sc = frcp(lm);
            rs += flog2(lm);
            a0 *= sc; a1 *= sc; a2 *= sc; a3 *= sc;
            pa3 = wave_shr1(a3);
        }
    };

    auto run8 = [&](int buf, int tb, bool guard) {
        // --- batched LDS gather: forced by inline asm (24 ds_read_b32) ---
        // generic->LDS offset: low 32 bits of a __shared__ pointer
        unsigned base = (unsigned)(size_t)(&ldsr[buf][0][0]);
        unsigned ab = base + 4u * 1;
        unsigned a1a = base + 4u * (unsigned)c1;
        unsigned a3a = base + 4u * (unsigned)c3;
        float g0,g1,g2,g3,g4,g5,g6,g7,g8,g9,g10,g11,
              g12,g13,g14,g15,g16,g17,g18,g19,g20,g21,g22,g23;
        asm volatile(
            "ds_read_b32 %0,  %24 offset:0\n\t"
            "ds_read_b32 %1,  %25 offset:0\n\t"
            "ds_read_b32 %2,  %26 offset:0\n\t"
            "ds_read_b32 %3,  %24 offset:2048\n\t"
            "ds_read_b32 %4,  %25 offset:2048\n\t"
            "ds_read_b32 %5,  %26 offset:2048\n\t"
            "ds_read_b32 %6,  %24 offset:4096\n\t"
            "ds_read_b32 %7,  %25 offset:4096\n\t"
            "ds_read_b32 %8,  %26 offset:4096\n\t"
            "ds_read_b32 %9,  %24 offset:6144\n\t"
            "ds_read_b32 %10, %25 offset:6144\n\t"
            "ds_read_b32 %11, %26 offset:6144\n\t"
            "ds_read_b32 %12, %24 offset:8192\n\t"
            "ds_read_b32 %13, %25 offset:8192\n\t"
            "ds_read_b32 %14, %26 offset:8192\n\t"
            "ds_read_b32 %15, %24 offset:10240\n\t"
            "ds_read_b32 %16, %25 offset:10240\n\t"
            "ds_read_b32 %17, %26 offset:10240\n\t"
            "ds_read_b32 %18, %24 offset:12288\n\t"
            "ds_read_b32 %19, %25 offset:12288\n\t"
            "ds_read_b32 %20, %26 offset:12288\n\t"
            "ds_read_b32 %21, %24 offset:14336\n\t"
            "ds_read_b32 %22, %25 offset:14336\n\t"
            "ds_read_b32 %23, %26 offset:14336\n\t"
            "s_waitcnt lgkmcnt(0)"
            : "=&v"(g0), "=&v"(g1), "=&v"(g2), "=&v"(g3), "=&v"(g4), "=&v"(g5),
              "=&v"(g6), "=&v"(g7), "=&v"(g8), "=&v"(g9), "=&v"(g10), "=&v"(g11),
              "=&v"(g12), "=&v"(g13), "=&v"(g14), "=&v"(g15), "=&v"(g16), "=&v"(g17),
              "=&v"(g18), "=&v"(g19), "=&v"(g20), "=&v"(g21), "=&v"(g22), "=&v"(g23)
            : "v"(ab), "v"(a1a), "v"(a3a));

        float eb[8], e1[8], e3[8];
        float gb[24] = {g0,g1,g2,g3,g4,g5,g6,g7,g8,g9,g10,g11,
                        g12,g13,g14,g15,g16,g17,g18,g19,g20,g21,g22,g23};
        #pragma unroll
        for (int i = 0; i < 8; ++i) {
            eb[i] = fexp2(fmaf(gb[3 * i],     LOG2E, SHIFT));
            e1[i] = fexp2(fmaf(gb[3 * i + 1], LOG2E, SHIFT));
            e3[i] = fexp2(fmaf(gb[3 * i + 2], LOG2E, SHIFT));
        }
        #pragma unroll
        for (int i = 0; i < 8; ++i) {
            float ex = eb[i] * m0, ey = e1[i] * m1;
            float ez = eb[i] * m2, ew = e3[i] * m3;
            float n0 = (a0 + pa3) * ex;
            float n1 = fmaf(sk1, pa3, a1 + a0) * ey;
            float n2 = (a2 + a1) * ez;
            float n3 = fmaf(sk3, a1, a3 + a2) * ew;
            if (!guard || (tb + i < Tin)) { a0 = n0; a1 = n1; a2 = n2; a3 = n3; }
            pa3 = wave_shr1(a3);
        }
    };

    issue(0, 0); issue(1, 1); issue(2, 2);          // 48 DMAs in flight
    const int Kf = (Tin - 1) / 8;                   // full chunks
    const int K  = (Tin - 1 + 7) / 8;               // total chunks
    for (int k = 0; k < Kf; ++k) {
        waitcnt_vm32();                             // chunk k landed
        issue(k + 3, (k + 3) & 3);                  // into buffer freed by k-1
        run8(k & 3, 0, false);
        if (k & 1) renorm();
    }
    if (K > Kf) {                                   // guarded tail chunk
        waitcnt_vm32();
        run8(Kf & 3, 1 + 8 * Kf, true);
    }
    waitcnt_vm0();                                  // drain DMA before endpgm

    const int last = 2 * Lt;
    const int prev = max(last - 1, 0);
    const int lr = last & 3, lidx = last >> 2;
    float av = (lr == 0) ? a0 : (lr == 1) ? a1 : (lr == 2) ? a2 : a3;
    float a_last = __shfl(av, lidx);
    const int pr = prev & 3, pidx = prev >> 2;
    float pv = (pr == 0) ? a0 : (pr == 1) ? a1 : (pr == 2) ? a2 : a3;
    float a_prev = __shfl(pv, pidx);

    float sum = a_last + a_prev;
    float loss = 0.f;
    if (sum > 0.f)
        loss = -(flog2(sum) + rs - SHIFT * (float)Tin) * LN2;
    if (lane == 0) loss_ws[b] = loss;
}

// ---------------- Fallback (log-domain single pass) ----------------
__global__ __launch_bounds__(64) void ctc_alpha_fb(
    const float* __restrict__ logp, const int* __restrict__ in_len,
    const int* __restrict__ tgt, const int* __restrict__ tgt_len,
    float* __restrict__ loss_ws)
{
    const int b = blockIdx.x, lane = threadIdx.x;
    const int Tin = in_len[b], Lt = tgt_len[b];
    const int ext_len = 2 * Lt + 1;
    const int* tg = tgt + b * CT_S;
    const int s0 = 4 * lane, s1 = s0 + 1, s3 = s0 + 3;
    const int i1 = min((s1 - 1) >> 1, CT_S - 1);
    const int i3 = min((s3 - 1) >> 1, CT_S - 1);
    const int c1 = tg[i1], c3 = tg[i3];
    const bool skip1 = (s1 >= 3) && (s1 < CT_Se) && (c1 != tg[max(i1 - 1, 0)]);
    const bool skip3 = (s3 >= 3) && (s3 < CT_Se) && (c3 != tg[max(i3 - 1, 0)]);
    const bool v0 = s0 < ext_len, v1 = s1 < ext_len;
    const bool v2 = (s0 + 2) < ext_len, v3 = s3 < ext_len;
    const float* row0 = logp + (long long)b * CT_V;
    const long long stride = (long long)CT_B * CT_V;
    float a0 = NEGF, a1 = NEGF, a2 = NEGF, a3 = NEGF;
    if (lane == 0) {
        a0 = row0[1] * LOG2E;
        if (ext_len > 1) a1 = row0[c1] * LOG2E;
    }
    float3 E0, E1, E2, E3;
    auto ld = [&](float3& e, int t) {
        int tt = min(t, CT_T - 1);
        const float* r = row0 + (long long)tt * stride;
        e.x = r[1] * LOG2E; e.y = r[c1] * LOG2E; e.z = r[c3] * LOG2E;
    };
    auto step = [&](const float3& e) {
        float pa3 = __shfl_up(a3, 1);
        if (lane == 0) pa3 = NEGF;
        float z1 = skip1 ? pa3 : NEGF;
        float z3 = skip3 ? a1 : NEGF;
        float n0 = v0 ? lae2_b2(a0, pa3)    + e.x : NEGF;
        float n1 = v1 ? lae3_b2(a1, a0, z1) + e.y : NEGF;
        float n2 = v2 ? lae2_b2(a2, a1)     + e.x : NEGF;
        float n3 = v3 ? lae3_b2(a3, a2, z3) + e.z : NEGF;
        a0 = n0; a1 = n1; a2 = n2; a3 = n3;
    };
    ld(E0, 1); ld(E1, 2); ld(E2, 3); ld(E3, 4);
    for (int t = 1; t < Tin; t += 4) {
        step(E0); ld(E0, t + 4);
        if (t + 1 < Tin) { step(E1); ld(E1, t + 5); }
        if (t + 2 < Tin) { step(E2); ld(E2, t + 6); }
        if (t + 3 < Tin) { step(E3); ld(E3, t + 7); }
    }
    const int last = 2 * Lt, prev = max(last - 1, 0);
    const int lr = last & 3, lidx = last >> 2;
    float av = (lr == 0) ? a0 : (lr == 1) ? a1 : (lr == 2) ? a2 : a3;
    float a_last = __shfl(av, lidx);
    const int pr = prev & 3, pidx = prev >> 2;
    float pv = (pr == 0) ? a0 : (pr == 1) ? a1 : (pr == 2) ? a2 : a3;
    float a_prev = __shfl(pv, pidx);
    float loglik = lae2_b2(a_last, a_prev) * LN2;
    float loss = (loglik < 0.5f * NEGF) ? 0.0f : -loglik;
    if (lane == 0) loss_ws[b] = loss;
}

__global__ __launch_bounds__(64) void ctc_sum(const float* __restrict__ loss_ws,
                                              float* __restrict__ out)
{
    float v = loss_ws[threadIdx.x];
    #pragma unroll
    for (int o = 32; o > 0; o >>= 1) v += __shfl_down(v, o);
    if (threadIdx.x == 0) out[0] = v;
}

extern "C" void kernel_launch(void* const* d_in, const int* in_sizes, int n_in,
                              void* d_out, int out_size, void* d_ws, size_t ws_size,
                              hipStream_t stream) {
    const float* logp    = (const float*)d_in[0];
    const int*   in_len  = (const int*)d_in[1];
    const int*   tgt     = (const int*)d_in[2];
    const int*   tgt_len = (const int*)d_in[3];
    float* out = (float*)d_out;
    float* loss_ws = (float*)d_ws;   // needs only 256 B

    if (ws_size >= 256 * sizeof(float)) {
        hipLaunchKernelGGL(ctc_alpha, dim3(CT_B), dim3(64), 0, stream,
                           logp, in_len, tgt, tgt_len, loss_ws);
    } else {
        hipLaunchKernelGGL(ctc_alpha_fb, dim3(CT_B), dim3(64), 0, stream,
                           logp, in_len, tgt, tgt_len, loss_ws);
    }
    hipLaunchKernelGGL(ctc_sum, dim3(1), dim3(64), 0, stream, loss_ws, out);
}